// Round 6
// baseline (194.547 us; speedup 1.0000x reference)
//
#include <hip/hip_runtime.h>
#include <hip/hip_cooperative_groups.h>

namespace cg = cooperative_groups;

#define B 32
#define S 512
#define D 384
#define T 3072
#define FPB 64             // frames per gather block
#define D4 (D/4)           // 96 float4 per frame
#define NT 256
#define BPR (T/FPB)        // 48 blocks per batch row
#define NBLK (BPR*B)       // 1536 blocks (co-resident: 8 blk/CU * 256 CU = 2048)

typedef float f32x4 __attribute__((ext_vector_type(4)));

// d_out offsets (floats), concatenated in reference return order
#define OFF_OUT  0
#define OFF_DUR  (B*T*D)
#define OFF_MLEN (OFF_DUR + B*S)
#define OFF_MASK (OFF_MLEN + B)

// Single cooperative kernel: blocks 0..31 do durations+cumsum+idx scatter,
// grid.sync(), then all blocks gather-copy. Removes the phase-1 dispatch gap.
__global__ __launch_bounds__(NT) void fused_kernel(
    const float* __restrict__ x, const float* __restrict__ logd,
    const int* __restrict__ max_len_p, float* __restrict__ outp,
    int* __restrict__ idx_ws, int* __restrict__ mlen_ws)
{
    const int bid = blockIdx.x;
    const int tid = threadIdx.x;

    // ---- Phase 1 (blocks 0..B-1): row bid ----
    if (bid < B) {
        const int b = bid;
        const int s0 = tid * 2;
        const float* ldrow = logd + b * S;
        float dr0 = fmaxf(rintf(expf(ldrow[s0])     - 1.0f), 0.0f);  // half-even, matches jnp.round
        float dr1 = fmaxf(rintf(expf(ldrow[s0 + 1]) - 1.0f), 0.0f);
        int d0 = (int)dr0, d1 = (int)dr1;

        outp[OFF_DUR + b * S + s0]     = dr0;
        outp[OFF_DUR + b * S + s0 + 1] = dr1;

        // inclusive scan of pair sums across 256 threads
        const int lane = tid & 63;
        const int wave = tid >> 6;
        int v = d0 + d1;
        #pragma unroll
        for (int off = 1; off < 64; off <<= 1) {
            int u = __shfl_up(v, off, 64);
            if (lane >= off) v += u;
        }
        __shared__ int wsum[NT / 64];
        if (lane == 63) wsum[wave] = v;
        __syncthreads();
        if (tid == 0) {
            int acc = 0;
            #pragma unroll
            for (int w = 0; w < NT / 64; ++w) { int t = wsum[w]; wsum[w] = acc; acc += t; }
        }
        __syncthreads();
        const int inc = v + wsum[wave];     // inclusive through s0+1
        // scatter: idx[b,t] = s for t in [cum[s-1], cum[s])
        int st1 = inc - d1;                 // start of s0+1 range
        int st0 = st1 - d0;                 // start of s0 range
        int en0 = min(st1, T), en1 = min(inc, T);
        for (int t = st0; t < en0; ++t) idx_ws[b * T + t] = s0;
        for (int t = st1; t < en1; ++t) idx_ws[b * T + t] = s0 + 1;

        if (tid == NT - 1) {
            int ml = min(inc, max_len_p[0]);
            mlen_ws[b] = ml;
            outp[OFF_MLEN + b] = (float)ml;
        }
    }

    cg::this_grid().sync();   // device-scope release/acquire of idx_ws/mlen_ws

    // ---- Phase 2 (all blocks): gather-copy ----
    __shared__ int sidx[FPB];
    const int b  = bid / BPR;
    const int t0 = (bid % BPR) * FPB;

    const int mlen = mlen_ws[b];            // uniform -> scalar load
    if (tid < FPB) {
        sidx[tid] = idx_ws[b * T + t0 + tid];
        const int t = t0 + tid;
        outp[OFF_MASK + (size_t)b * T + t] = (t < mlen) ? 0.0f : 1.0f;
    }
    __syncthreads();

    const f32x4* x4 = (const f32x4*)(x + (size_t)b * S * D);
    f32x4* o4 = (f32x4*)(outp + OFF_OUT + (size_t)b * T * D + (size_t)t0 * D);

    #pragma unroll
    for (int i = 0; i < (FPB * D4) / NT; ++i) {   // 24 iterations
        int w = tid + i * NT;
        int f = w / D4;
        int e = w - f * D4;
        int t = t0 + f;
        f32x4 val = (f32x4)(0.f);
        if (t < mlen) val = x4[(size_t)sidx[f] * D4 + e];
        o4[(size_t)f * D4 + e] = val;
    }
}

extern "C" void kernel_launch(void* const* d_in, const int* in_sizes, int n_in,
                              void* d_out, int out_size, void* d_ws, size_t ws_size,
                              hipStream_t stream) {
    const float* x      = (const float*)d_in[0];
    const float* logd   = (const float*)d_in[1];
    const int*   maxlen = (const int*)d_in[2];
    float* out = (float*)d_out;

    int* idx_ws  = (int*)d_ws;
    int* mlen_ws = idx_ws + B * T;

    void* args[] = {(void*)&x, (void*)&logd, (void*)&maxlen,
                    (void*)&out, (void*)&idx_ws, (void*)&mlen_ws};
    hipLaunchCooperativeKernel((void*)fused_kernel, dim3(NBLK), dim3(NT),
                               args, 0, stream);
}

// Round 7
// 30.065 us; speedup vs baseline: 6.4709x; 6.4709x over previous
//
#include <hip/hip_runtime.h>

#define B 32
#define S 512
#define D 384
#define T 3072
#define FPB 64             // frames per block
#define D4 (D/4)           // 96 float4 per frame
#define NT 256
#define BPR (T/FPB)        // 48 blocks per batch row

typedef float f32x4 __attribute__((ext_vector_type(4)));

// d_out offsets (floats), concatenated in reference return order
#define OFF_OUT  0
#define OFF_DUR  (B*T*D)
#define OFF_MLEN (OFF_DUR + B*S)
#define OFF_MASK (OFF_MLEN + B)

// Single dispatch, zero cross-block dependencies: every block recomputes its
// row's durations + cumsum (512 exps + one shfl-scan, ~hidden under 8-deep
// occupancy), then searchsorted + copy. Three-path epilogue: pure-fill blocks
// (t0 >= mlen, ~half at mel_len~1500) skip search and x entirely; full-copy
// blocks drop per-store guards. Plain stores (nt regressed in R3/R4).
__global__ __launch_bounds__(NT) void upsample_kernel(
    const float* __restrict__ x, const float* __restrict__ logd,
    const int* __restrict__ max_len_p, float* __restrict__ outp)
{
    __shared__ int cum_s[S];
    __shared__ int wsum[NT / 64];
    __shared__ int sidx[FPB];
    __shared__ int mlen_sh;

    const int bid = blockIdx.x;
    const int b   = bid / BPR;
    const int t0  = (bid % BPR) * FPB;
    const int tid = threadIdx.x;
    const int lane = tid & 63;
    const int wave = tid >> 6;

    // ---- Phase A: durations + inclusive cumsum of row b ----
    const int s0 = tid * 2;
    const float* ldrow = logd + b * S;
    float dr0 = fmaxf(rintf(expf(ldrow[s0])     - 1.0f), 0.0f);  // half-even = jnp.round
    float dr1 = fmaxf(rintf(expf(ldrow[s0 + 1]) - 1.0f), 0.0f);
    int d1 = (int)dr1;
    int v = (int)dr0 + d1;
    #pragma unroll
    for (int off = 1; off < 64; off <<= 1) {
        int u = __shfl_up(v, off, 64);
        if (lane >= off) v += u;
    }
    if (lane == 63) wsum[wave] = v;
    __syncthreads();
    if (tid == 0) {
        int acc = 0;
        #pragma unroll
        for (int w = 0; w < NT / 64; ++w) { int t = wsum[w]; wsum[w] = acc; acc += t; }
    }
    __syncthreads();
    const int inc = v + wsum[wave];          // inclusive through s0+1
    cum_s[s0]     = inc - d1;
    cum_s[s0 + 1] = inc;
    if (tid == NT - 1) mlen_sh = min(inc, max_len_p[0]);

    if (bid % BPR == 0) {                    // once per row: dur + mlen outputs
        outp[OFF_DUR + b * S + s0]     = dr0;
        outp[OFF_DUR + b * S + s0 + 1] = dr1;
    }
    __syncthreads();
    const int mlen = mlen_sh;
    if (bid % BPR == 0 && tid == 0) outp[OFF_MLEN + b] = (float)mlen;

    // mask for this block's frames
    if (tid < FPB) {
        const int t = t0 + tid;
        outp[OFF_MASK + (size_t)b * T + t] = (t < mlen) ? 0.0f : 1.0f;
    }

    f32x4* o4 = (f32x4*)(outp + OFF_OUT + (size_t)b * T * D + (size_t)t0 * D);

    // ---- Path 1: pure zero-fill (no search, no x) ----
    if (t0 >= mlen) {
        #pragma unroll
        for (int i = 0; i < (FPB * D4) / NT; ++i) {
            int w = tid + i * NT;
            o4[w] = (f32x4)(0.f);
        }
        return;
    }

    // searchsorted for this block's frames (valid ones)
    if (tid < FPB) {
        const int t = t0 + tid;
        int lo = 0;
        if (t < mlen) {
            int hi = S;
            while (lo < hi) {
                int mid = (lo + hi) >> 1;
                if (cum_s[mid] <= t) lo = mid + 1; else hi = mid;
            }
            if (lo > S - 1) lo = S - 1;
        }
        sidx[tid] = lo;
    }
    __syncthreads();

    const f32x4* x4 = (const f32x4*)(x + (size_t)b * S * D);

    // ---- Path 2: fully valid block (no guards) ----
    if (t0 + FPB <= mlen) {
        #pragma unroll
        for (int i = 0; i < (FPB * D4) / NT; ++i) {
            int w = tid + i * NT;
            int f = w / D4;
            int e = w - f * D4;
            o4[w] = x4[(size_t)sidx[f] * D4 + e];
        }
        return;
    }

    // ---- Path 3: boundary block (guarded) ----
    #pragma unroll
    for (int i = 0; i < (FPB * D4) / NT; ++i) {
        int w = tid + i * NT;
        int f = w / D4;
        int e = w - f * D4;
        int t = t0 + f;
        f32x4 val = (f32x4)(0.f);
        if (t < mlen) val = x4[(size_t)sidx[f] * D4 + e];
        o4[w] = val;
    }
}

extern "C" void kernel_launch(void* const* d_in, const int* in_sizes, int n_in,
                              void* d_out, int out_size, void* d_ws, size_t ws_size,
                              hipStream_t stream) {
    const float* x      = (const float*)d_in[0];
    const float* logd   = (const float*)d_in[1];
    const int*   maxlen = (const int*)d_in[2];
    float* out = (float*)d_out;

    upsample_kernel<<<BPR * B, NT, 0, stream>>>(x, logd, maxlen, out);
}

// Round 8
// 29.573 us; speedup vs baseline: 6.5785x; 1.0166x over previous
//
#include <hip/hip_runtime.h>

#define B 32
#define S 512
#define D 384
#define T 3072
#define FPB 64             // frames per block
#define D4 (D/4)           // 96 float4 per frame
#define NT 256
#define BPR (T/FPB)        // 48 blocks per batch row
#define NW (NT/64)         // 4 waves

typedef float f32x4 __attribute__((ext_vector_type(4)));
typedef float f32x2 __attribute__((ext_vector_type(2)));

// d_out offsets (floats), concatenated in reference return order
#define OFF_OUT  0
#define OFF_DUR  (B*T*D)
#define OFF_MLEN (OFF_DUR + B*S)
#define OFF_MASK (OFF_MLEN + B)

// Single dispatch, zero cross-block deps; per-block row recompute with a
// minimized pre-store critical path: float2 logd load, ONE barrier for the
// wave-offset exchange (each thread privately prefix-sums the 4 wave totals
// -> also yields row total, so no mlen broadcast/barrier), pure-fill blocks
// exit before the cum_s barrier. Plain stores (nt regressed R3/R4).
__global__ __launch_bounds__(NT) void upsample_kernel(
    const float* __restrict__ x, const float* __restrict__ logd,
    const int* __restrict__ max_len_p, float* __restrict__ outp)
{
    __shared__ int cum_s[S];
    __shared__ int wsum[NW];
    __shared__ int sidx[FPB];

    const int bid = blockIdx.x;
    const int b   = bid / BPR;
    const int t0  = (bid % BPR) * FPB;
    const int tid = threadIdx.x;
    const int lane = tid & 63;
    const int wave = tid >> 6;

    const int max_len = max_len_p[0];          // uniform s_load, issue early

    // ---- Phase A: durations + inclusive cumsum of row b ----
    const int s0 = tid * 2;
    f32x2 ld = *(const f32x2*)(logd + b * S + s0);
    float dr0 = fmaxf(rintf(expf(ld.x) - 1.0f), 0.0f);  // half-even = jnp.round
    float dr1 = fmaxf(rintf(expf(ld.y) - 1.0f), 0.0f);
    int d1 = (int)dr1;
    int v = (int)dr0 + d1;
    #pragma unroll
    for (int off = 1; off < 64; off <<= 1) {
        int u = __shfl_up(v, off, 64);
        if (lane >= off) v += u;
    }
    if (lane == 63) wsum[wave] = v;
    __syncthreads();                            // the ONLY pre-decision barrier
    // each thread: private prefix of wave totals + row total (no serial pass)
    int w0 = wsum[0], w1 = wsum[1], w2 = wsum[2], w3 = wsum[3];
    int woff = (wave > 0 ? w0 : 0) + (wave > 1 ? w1 : 0) + (wave > 2 ? w2 : 0);
    const int total = w0 + w1 + w2 + w3;
    const int mlen = min(total, max_len);

    const int inc = v + woff;                   // inclusive through s0+1

    if (bid % BPR == 0) {                       // once per row: dur + mlen
        *(f32x2*)(outp + OFF_DUR + b * S + s0) = (f32x2){dr0, dr1};
        if (tid == 0) outp[OFF_MLEN + b] = (float)mlen;
    }
    if (tid < FPB) {                            // mask for this block's frames
        const int t = t0 + tid;
        outp[OFF_MASK + (size_t)b * T + t] = (t < mlen) ? 0.0f : 1.0f;
    }

    f32x4* o4 = (f32x4*)(outp + OFF_OUT + (size_t)b * T * D + (size_t)t0 * D);

    // ---- Path 1: pure zero-fill (needs only mlen; skips cum_s entirely) ----
    if (t0 >= mlen) {
        #pragma unroll
        for (int i = 0; i < (FPB * D4) / NT; ++i)
            o4[tid + i * NT] = (f32x4)(0.f);
        return;
    }

    cum_s[s0]     = inc - d1;
    cum_s[s0 + 1] = inc;
    __syncthreads();

    // searchsorted for this block's frames
    if (tid < FPB) {
        const int t = t0 + tid;
        int lo = 0;
        if (t < mlen) {
            int hi = S;
            while (lo < hi) {
                int mid = (lo + hi) >> 1;
                if (cum_s[mid] <= t) lo = mid + 1; else hi = mid;
            }
            if (lo > S - 1) lo = S - 1;
        }
        sidx[tid] = lo;
    }
    __syncthreads();

    const f32x4* x4 = (const f32x4*)(x + (size_t)b * S * D);

    // ---- Path 2: fully valid block (no guards) ----
    if (t0 + FPB <= mlen) {
        #pragma unroll
        for (int i = 0; i < (FPB * D4) / NT; ++i) {
            int w = tid + i * NT;
            int f = w / D4;
            int e = w - f * D4;
            o4[w] = x4[(size_t)sidx[f] * D4 + e];
        }
        return;
    }

    // ---- Path 3: boundary block (guarded) ----
    #pragma unroll
    for (int i = 0; i < (FPB * D4) / NT; ++i) {
        int w = tid + i * NT;
        int f = w / D4;
        int e = w - f * D4;
        int t = t0 + f;
        f32x4 val = (f32x4)(0.f);
        if (t < mlen) val = x4[(size_t)sidx[f] * D4 + e];
        o4[w] = val;
    }
}

extern "C" void kernel_launch(void* const* d_in, const int* in_sizes, int n_in,
                              void* d_out, int out_size, void* d_ws, size_t ws_size,
                              hipStream_t stream) {
    const float* x      = (const float*)d_in[0];
    const float* logd   = (const float*)d_in[1];
    const int*   maxlen = (const int*)d_in[2];
    float* out = (float*)d_out;

    upsample_kernel<<<BPR * B, NT, 0, stream>>>(x, logd, maxlen, out);
}